// Round 4
// baseline (269.438 us; speedup 1.0000x reference)
//
#include <hip/hip_runtime.h>
#include <math.h>

constexpr int NNODES = 80000;
constexpr int NEDGES = 1280000;

typedef __attribute__((ext_vector_type(8))) short bf16x8;
typedef __attribute__((ext_vector_type(16))) float f32x16;
typedef __attribute__((ext_vector_type(4))) float f32x4;
typedef __attribute__((ext_vector_type(4))) int i32x4;

__device__ __forceinline__ short f2b(float f) {
    unsigned u = __builtin_bit_cast(unsigned, f);
    u = u + 0x7FFFu + ((u >> 16) & 1u);          // RNE to bf16
    return (short)(u >> 16);
}
__device__ __forceinline__ unsigned pk2(float lo, float hi) {
    return ((unsigned)(unsigned short)f2b(hi) << 16) | (unsigned)(unsigned short)f2b(lo);
}

// K0: fold W3/b3 through Wh; emit W35 and Wo as bf16 fragments:
// frag content at lane l, elem i:  W[32b + (l&31)][8*(l>>5) + i (+16ks for Wo)]
// (serves as A operand: row = l&31, k-slot = 8*(l>>5)+i)
// c[j] = bh[j] + sum_m Wh[j][m]*b3[m]
__global__ void k_pre(const float* __restrict__ W3, const float* __restrict__ b3,
                      const float* __restrict__ Wh, const float* __restrict__ bh,
                      const float* __restrict__ Wo,
                      short* __restrict__ W35F, short* __restrict__ WoF,
                      float* __restrict__ c) {
    int t = threadIdx.x;            // 1024 threads
    {
        int b = t >> 9, l = (t >> 3) & 63, i = t & 7;
        int k = 8 * (l >> 5) + i;
        int j = 32 * b + (l & 31);
        float s = 0.f;
#pragma unroll
        for (int m = 0; m < 64; ++m) s += Wh[j * 64 + m] * W3[m * 16 + k];
        W35F[t] = f2b(s);
    }
#pragma unroll
    for (int q = 0; q < 4; ++q) {
        int idx = q * 1024 + t;
        int b  = idx >> 11;
        int ks = (idx >> 9) & 3;
        int l  = (idx >> 3) & 63;
        int i  = idx & 7;
        int k  = 16 * ks + 8 * (l >> 5) + i;
        int j  = 32 * b + (l & 31);
        WoF[idx] = f2b(Wo[j * 64 + k]);
    }
    if (t < 64) {
        float cc = bh[t];
#pragma unroll
        for (int m = 0; m < 64; ++m) cc += Wh[t * 64 + m] * b3[m];
        c[t] = cc;
    }
}

// K1: per-node  n2 = (h@W1^T + b1 + e@W2^T + b2) @ Wh^T   (unchanged)
__global__ __launch_bounds__(256) void k_node(
    const float* __restrict__ h, const float* __restrict__ e,
    const float* __restrict__ W1, const float* __restrict__ b1,
    const float* __restrict__ W2, const float* __restrict__ b2,
    const float* __restrict__ Wh, float* __restrict__ n2) {
    __shared__ float sW1T[64 * 65];
    __shared__ float sW2T[32 * 65];
    __shared__ float sWhT[64 * 65];
    __shared__ float sStage[4][160];

    int tid = threadIdx.x;
    for (int idx = tid; idx < 64 * 64; idx += 256) {
        int j = idx >> 6, k = idx & 63;
        sW1T[k * 65 + j] = W1[idx];
        sWhT[k * 65 + j] = Wh[idx];
    }
    for (int idx = tid; idx < 64 * 32; idx += 256) {
        int j = idx >> 5, k = idx & 31;
        sW2T[k * 65 + j] = W2[idx];
    }
    __syncthreads();

    int w = tid >> 6, lane = tid & 63;
    float* hs = &sStage[w][0];
    float* es = &sStage[w][64];
    float* ns = &sStage[w][96];
    int waveId = blockIdx.x * 4 + w;
    float bb = b1[lane] + b2[lane];

    for (int i = 0; i < 20; ++i) {
        int n = waveId * 20 + i;
        hs[lane] = h[n * 64 + lane];
        if (lane < 32) es[lane] = e[n * 32 + lane];
        float a = bb;
#pragma unroll
        for (int k = 0; k < 64; ++k) a += hs[k] * sW1T[k * 65 + lane];
#pragma unroll
        for (int k = 0; k < 32; ++k) a += es[k] * sW2T[k * 65 + lane];
        ns[lane] = a;
        float o = 0.f;
#pragma unroll
        for (int k = 0; k < 64; ++k) o += ns[k] * sWhT[k * 65 + lane];
        n2[n * 64 + lane] = o;
    }
}

// K2: no-LDS edge MLP. Swapped MFMA orientation: D[ch][edge], col(lane&31)=edge.
//  P   = mfma(W35frag, eijT_frag, C=c_acc)          (2 MFMA)
//  v   = P + n2[src] + n2[dst]   (per-lane float4 gathers, 32 ch/lane)
//  hm  = elu(v); pack bf16 pairs; 8x permlane32_swap -> B-frags of hmT
//  out = mfma(Wofrag, hmT_frag, C=bo_acc)           (8 MFMA), f32x4 NT stores
__global__ __launch_bounds__(256, 2) void k_edge(
    const float* __restrict__ eij, const int* __restrict__ src, const int* __restrict__ dst,
    const float* __restrict__ n2, const short* __restrict__ W35F, const short* __restrict__ WoF,
    const float* __restrict__ c, const float* __restrict__ bo,
    float* __restrict__ out) {
    int tid = threadIdx.x;
    int lane = tid & 63;
    int hf = lane >> 5;
    int l31 = lane & 31;

    // weight A-fragments (persistent)
    bf16x8 w35A0 = *(const bf16x8*)(W35F + (0 * 64 + lane) * 8);
    bf16x8 w35A1 = *(const bf16x8*)(W35F + (1 * 64 + lane) * 8);
    bf16x8 woA[2][4];
#pragma unroll
    for (int b = 0; b < 2; ++b)
#pragma unroll
        for (int ks = 0; ks < 4; ++ks)
            woA[b][ks] = *(const bf16x8*)(WoF + ((b * 4 + ks) * 64 + lane) * 8);

    // c / bo as MFMA C operands: elem[4q+j] = v[8q + 4hf + j] (+32 for the hi block)
    f32x16 cA0, cA1, boA0, boA1;
#pragma unroll
    for (int q = 0; q < 4; ++q) {
        f32x4 t0 = *(const f32x4*)(c + 8 * q + 4 * hf);
        f32x4 t1 = *(const f32x4*)(c + 32 + 8 * q + 4 * hf);
        f32x4 u0 = *(const f32x4*)(bo + 8 * q + 4 * hf);
        f32x4 u1 = *(const f32x4*)(bo + 32 + 8 * q + 4 * hf);
#pragma unroll
        for (int j = 0; j < 4; ++j) {
            cA0[4 * q + j] = t0[j];  cA1[4 * q + j] = t1[j];
            boA0[4 * q + j] = u0[j]; boA1[4 * q + j] = u1[j];
        }
    }

    int gw = (blockIdx.x * 256 + tid) >> 6;    // global wave id, 0..9999
    int base0 = gw * 128;                      // 4 tiles * 32 edges

    // prefetch tile 0 idx + eij
    int sv = src[base0 + l31];
    int dv = dst[base0 + l31];
    f32x4 e0 = *(const f32x4*)(eij + (size_t)(base0 + l31) * 16 + 8 * hf);
    f32x4 e1 = *(const f32x4*)(eij + (size_t)(base0 + l31) * 16 + 8 * hf + 4);

    for (int tt = 0; tt < 4; ++tt) {
        int edge = base0 + tt * 32 + l31;

        // issue this tile's gathers (each lane: its edge, its 32 channels)
        const f32x4* ps = (const f32x4*)(n2 + (size_t)sv * 64 + 4 * hf);
        const f32x4* pd = (const f32x4*)(n2 + (size_t)dv * 64 + 4 * hf);
        f32x4 gs[8], gd[8];
#pragma unroll
        for (int q = 0; q < 8; ++q) gs[q] = ps[2 * q];
#pragma unroll
        for (int q = 0; q < 8; ++q) gd[q] = pd[2 * q];

        // prefetch next tile idx + eij (branchless, in-bounds)
        int en = (tt < 3) ? (edge + 32) : edge;
        int svn = src[en], dvn = dst[en];
        f32x4 e0n = *(const f32x4*)(eij + (size_t)en * 16 + 8 * hf);
        f32x4 e1n = *(const f32x4*)(eij + (size_t)en * 16 + 8 * hf + 4);

        // eijT B-fragment: elem i = eij[edge][8*hf + i]
        i32x4 eu;
        eu[0] = (int)pk2(e0[0], e0[1]);
        eu[1] = (int)pk2(e0[2], e0[3]);
        eu[2] = (int)pk2(e1[0], e1[1]);
        eu[3] = (int)pk2(e1[2], e1[3]);
        bf16x8 ea = __builtin_bit_cast(bf16x8, eu);

        // P = W35 @ eijT + c
        f32x16 h0 = __builtin_amdgcn_mfma_f32_32x32x16_bf16(w35A0, ea, cA0, 0, 0, 0);
        f32x16 h1 = __builtin_amdgcn_mfma_f32_32x32x16_bf16(w35A1, ea, cA1, 0, 0, 0);

        // + gathers, ELU
#pragma unroll
        for (int q = 0; q < 4; ++q)
#pragma unroll
            for (int j = 0; j < 4; ++j) {
                float v0 = h0[4 * q + j] + gs[q][j] + gd[q][j];
                float v1 = h1[4 * q + j] + gs[q + 4][j] + gd[q + 4][j];
                h0[4 * q + j] = v0 > 0.f ? v0 : __expf(v0) - 1.f;
                h1[4 * q + j] = v1 > 0.f ? v1 : __expf(v1) - 1.f;
            }

        // pack bf16 pairs: P0[Q] = ch(8Q+4hf+0,+1), P1[Q] = ch(8Q+4hf+2,+3)
        unsigned P0[8], P1[8];
#pragma unroll
        for (int Q = 0; Q < 4; ++Q) {
            P0[Q]     = pk2(h0[4 * Q], h0[4 * Q + 1]);
            P1[Q]     = pk2(h0[4 * Q + 2], h0[4 * Q + 3]);
            P0[Q + 4] = pk2(h1[4 * Q], h1[4 * Q + 1]);
            P1[Q + 4] = pk2(h1[4 * Q + 2], h1[4 * Q + 3]);
        }

        // out = Wo @ hmT + bo  (B-frags assembled via permlane32_swap)
        f32x16 o0 = boA0, o1 = boA1;
#pragma unroll
        for (int ks = 0; ks < 4; ++ks) {
            auto s0 = __builtin_amdgcn_permlane32_swap((int)P0[2 * ks], (int)P0[2 * ks + 1], false, false);
            auto s1 = __builtin_amdgcn_permlane32_swap((int)P1[2 * ks], (int)P1[2 * ks + 1], false, false);
            i32x4 fr; fr[0] = s0[0]; fr[1] = s1[0]; fr[2] = s0[1]; fr[3] = s1[1];
            bf16x8 b2 = __builtin_bit_cast(bf16x8, fr);
            o0 = __builtin_amdgcn_mfma_f32_32x32x16_bf16(woA[0][ks], b2, o0, 0, 0, 0);
            o1 = __builtin_amdgcn_mfma_f32_32x32x16_bf16(woA[1][ks], b2, o1, 0, 0, 0);
        }

        // stores: lane's edge row; ch groups 8q+4hf(+32)
        float* po = out + (size_t)edge * 64 + 4 * hf;
#pragma unroll
        for (int q = 0; q < 4; ++q) {
            f32x4 v0, v1;
#pragma unroll
            for (int j = 0; j < 4; ++j) { v0[j] = o0[4 * q + j]; v1[j] = o1[4 * q + j]; }
            __builtin_nontemporal_store(v0, (f32x4*)(po + 8 * q));
            __builtin_nontemporal_store(v1, (f32x4*)(po + 32 + 8 * q));
        }

        sv = svn; dv = dvn; e0 = e0n; e1 = e1n;
    }
}

extern "C" void kernel_launch(void* const* d_in, const int* in_sizes, int n_in,
                              void* d_out, int out_size, void* d_ws, size_t ws_size,
                              hipStream_t stream) {
    const float* h   = (const float*)d_in[0];
    const float* e   = (const float*)d_in[1];
    const float* eij = (const float*)d_in[2];
    const int*   src = (const int*)d_in[3];
    const int*   dst = (const int*)d_in[4];
    const float* W1  = (const float*)d_in[5];
    const float* b1  = (const float*)d_in[6];
    const float* W2  = (const float*)d_in[7];
    const float* b2  = (const float*)d_in[8];
    const float* W3  = (const float*)d_in[9];
    const float* b3  = (const float*)d_in[10];
    const float* Wh  = (const float*)d_in[11];
    const float* bh  = (const float*)d_in[12];
    const float* Wo  = (const float*)d_in[13];
    const float* bo  = (const float*)d_in[14];
    float* out = (float*)d_out;

    float* n2   = (float*)d_ws;                        // 80000*64 f32 = 20.48 MB
    short* W35F = (short*)(n2 + (size_t)NNODES * 64);  // 1024 bf16 (frag order)
    short* WoF  = W35F + 1024;                         // 4096 bf16 (frag order)
    float* c    = (float*)(WoF + 4096);                // 64 f32

    hipLaunchKernelGGL(k_pre, dim3(1), dim3(1024), 0, stream, W3, b3, Wh, bh, Wo, W35F, WoF, c);
    hipLaunchKernelGGL(k_node, dim3(1000), dim3(256), 0, stream,
                       h, e, W1, b1, W2, b2, Wh, n2);
    // 2500 blocks * 4 waves * 4 tiles * 32 edges = 1,280,000
    hipLaunchKernelGGL(k_edge, dim3(2500), dim3(256), 0, stream,
                       eij, src, dst, n2, W35F, WoF, c, bo, out);
}

// Round 5
// 251.283 us; speedup vs baseline: 1.0722x; 1.0722x over previous
//
#include <hip/hip_runtime.h>
#include <math.h>

constexpr int NNODES = 80000;
constexpr int NEDGES = 1280000;

typedef __attribute__((ext_vector_type(8))) short bf16x8;
typedef __attribute__((ext_vector_type(4))) float f32x4;
typedef __attribute__((ext_vector_type(4))) int i32x4;
typedef __attribute__((ext_vector_type(2))) unsigned u32x2;

__device__ __forceinline__ short f2b(float f) {
    unsigned u = __builtin_bit_cast(unsigned, f);
    u = u + 0x7FFFu + ((u >> 16) & 1u);          // RNE to bf16
    return (short)(u >> 16);
}
__device__ __forceinline__ unsigned pk2(float lo, float hi) {
    return ((unsigned)(unsigned short)f2b(hi) << 16) | (unsigned)(unsigned short)f2b(lo);
}

// K0: fold W3/b3 through Wh; emit per-lane A-fragments for 16x16x32 MFMA.
// A-frag at lane l: A[row = l&15][k = 8*(l>>4) + i], i=0..7.
// W35F[m*512 + l*8 + i] = W35[16m + (l&15)][8*(l>>4)+i]  (0 for k>=16)
// WoF [f*512 + l*8 + i] = Wo [16*(f>>1) + (l&15)][32*(f&1) + 8*(l>>4) + i]
// c[j] = bh[j] + sum_m Wh[j][m]*b3[m]
__global__ void k_pre(const float* __restrict__ W3, const float* __restrict__ b3,
                      const float* __restrict__ Wh, const float* __restrict__ bh,
                      const float* __restrict__ Wo,
                      short* __restrict__ W35F, short* __restrict__ WoF,
                      float* __restrict__ c) {
    int t = threadIdx.x;            // 1024 threads
#pragma unroll
    for (int r = 0; r < 2; ++r) {
        int idx = r * 1024 + t;
        int m = idx >> 9, l = (idx >> 3) & 63, i = idx & 7;
        int k = 8 * (l >> 4) + i;
        int ch = 16 * m + (l & 15);
        float s = 0.f;
        if (k < 16) {
#pragma unroll
            for (int mm = 0; mm < 64; ++mm) s += Wh[ch * 64 + mm] * W3[mm * 16 + k];
        }
        W35F[idx] = f2b(s);
    }
#pragma unroll
    for (int r = 0; r < 4; ++r) {
        int idx = r * 1024 + t;
        int f = idx >> 9, l = (idx >> 3) & 63, i = idx & 7;
        int ch = 16 * (f >> 1) + (l & 15);
        int k = 32 * (f & 1) + 8 * (l >> 4) + i;
        WoF[idx] = f2b(Wo[ch * 64 + k]);
    }
    if (t < 64) {
        float cc = bh[t];
#pragma unroll
        for (int m = 0; m < 64; ++m) cc += Wh[t * 64 + m] * b3[m];
        c[t] = cc;
    }
}

// K1: per-node  n2' = (h@W1^T + b1 + e@W2^T + b2) @ Wh^T + 0.5*c
// (c folded in so the src+dst gather sum carries the full bias)
__global__ __launch_bounds__(256) void k_node(
    const float* __restrict__ h, const float* __restrict__ e,
    const float* __restrict__ W1, const float* __restrict__ b1,
    const float* __restrict__ W2, const float* __restrict__ b2,
    const float* __restrict__ Wh, const float* __restrict__ c,
    float* __restrict__ n2) {
    __shared__ float sW1T[64 * 65];
    __shared__ float sW2T[32 * 65];
    __shared__ float sWhT[64 * 65];
    __shared__ float sStage[4][160];

    int tid = threadIdx.x;
    for (int idx = tid; idx < 64 * 64; idx += 256) {
        int j = idx >> 6, k = idx & 63;
        sW1T[k * 65 + j] = W1[idx];
        sWhT[k * 65 + j] = Wh[idx];
    }
    for (int idx = tid; idx < 64 * 32; idx += 256) {
        int j = idx >> 5, k = idx & 31;
        sW2T[k * 65 + j] = W2[idx];
    }
    __syncthreads();

    int w = tid >> 6, lane = tid & 63;
    float* hs = &sStage[w][0];
    float* es = &sStage[w][64];
    float* ns = &sStage[w][96];
    int waveId = blockIdx.x * 4 + w;
    float bb = b1[lane] + b2[lane];
    float chalf = 0.5f * c[lane];

    for (int i = 0; i < 20; ++i) {
        int n = waveId * 20 + i;
        hs[lane] = h[n * 64 + lane];
        if (lane < 32) es[lane] = e[n * 32 + lane];
        float a = bb;
#pragma unroll
        for (int k = 0; k < 64; ++k) a += hs[k] * sW1T[k * 65 + lane];
#pragma unroll
        for (int k = 0; k < 32; ++k) a += es[k] * sW2T[k * 65 + lane];
        ns[lane] = a;
        float o = chalf;
#pragma unroll
        for (int k = 0; k < 64; ++k) o += ns[k] * sWhT[k * 65 + lane];
        n2[n * 64 + lane] = o;
    }
}

// K2: 16-edge tiles, 16x16x32 MFMA, lane = (e = l&15, g = l>>4).
//  P_m[16ch x 16e] = mfma(W35F_m, eijT)                  (4 MFMA, K-padded)
//  lane's gathers: f32x4 at n2'[node] + 16m + 4g  -> full 64B lines
//  hm = elu(P + gs + gd); pack pairs -> per-wave LDS; read back as B-frags
//  out_m2 = mfma(WoF[m2,ks], hmB[ks], C=bo)              (8 MFMA), f32x4 NT full-line stores
__global__ __launch_bounds__(256, 4) void k_edge(
    const float* __restrict__ eij, const int* __restrict__ src, const int* __restrict__ dst,
    const float* __restrict__ n2, const short* __restrict__ W35F, const short* __restrict__ WoF,
    const float* __restrict__ bo, float* __restrict__ out) {
    __shared__ __align__(16) short sWoF[4096];       // 8 KB: [f][lane][i]
    __shared__ __align__(16) unsigned shm[4][576];   // per-wave hm redistribution

    int tid = threadIdx.x, w = tid >> 6, lane = tid & 63;
    int e = lane & 15, g = lane >> 4;

    for (int idx = tid; idx < 512; idx += 256)
        ((ulonglong2*)sWoF)[idx] = ((const ulonglong2*)WoF)[idx];
    __syncthreads();

    bf16x8 w35[4];
#pragma unroll
    for (int m = 0; m < 4; ++m)
        w35[m] = *(const bf16x8*)(W35F + (m * 64 + lane) * 8);
    f32x4 boA[4];
#pragma unroll
    for (int m2 = 0; m2 < 4; ++m2)
        boA[m2] = *(const f32x4*)(bo + 16 * m2 + 4 * g);

    unsigned* hw = shm[w];
    const int eoff = (g & 1) * 8;
    const bool glow = (g < 2);

    int gw = blockIdx.x * 4 + w;        // 0..9999
    int base = gw * 128;                // 8 tiles * 16 edges
    int sv = src[base + e], dv = dst[base + e];
    f32x4 ev0 = *(const f32x4*)(eij + (size_t)(base + e) * 16 + eoff);
    f32x4 ev1 = *(const f32x4*)(eij + (size_t)(base + e) * 16 + eoff + 4);

    for (int t = 0; t < 8; ++t) {
        int erow = base + t * 16 + e;

        const float* ps = n2 + (size_t)sv * 64 + 4 * g;
        const float* pd = n2 + (size_t)dv * 64 + 4 * g;
        f32x4 gs0 = *(const f32x4*)(ps);       f32x4 gd0 = *(const f32x4*)(pd);
        f32x4 gs1 = *(const f32x4*)(ps + 16);  f32x4 gd1 = *(const f32x4*)(pd + 16);
        f32x4 gs2 = *(const f32x4*)(ps + 32);  f32x4 gd2 = *(const f32x4*)(pd + 32);
        f32x4 gs3 = *(const f32x4*)(ps + 48);  f32x4 gd3 = *(const f32x4*)(pd + 48);

        int nrow = base + (t < 7 ? (t + 1) * 16 : t * 16) + e;   // clamped prefetch
        int svn = src[nrow], dvn = dst[nrow];
        f32x4 ev0n = *(const f32x4*)(eij + (size_t)nrow * 16 + eoff);
        f32x4 ev1n = *(const f32x4*)(eij + (size_t)nrow * 16 + eoff + 4);

        // eij B-frag: col=e, k=8g+i; k>=16 zero-padded (g>=2)
        i32x4 ebi;
        ebi[0] = glow ? (int)pk2(ev0[0], ev0[1]) : 0;
        ebi[1] = glow ? (int)pk2(ev0[2], ev0[3]) : 0;
        ebi[2] = glow ? (int)pk2(ev1[0], ev1[1]) : 0;
        ebi[3] = glow ? (int)pk2(ev1[2], ev1[3]) : 0;
        bf16x8 eb = __builtin_bit_cast(bf16x8, ebi);

        const f32x4 z4 = {0.f, 0.f, 0.f, 0.f};
#define L1(M, GS, GD)                                                              \
        {                                                                          \
            f32x4 P = __builtin_amdgcn_mfma_f32_16x16x32_bf16(w35[M], eb, z4, 0, 0, 0); \
            float h0 = P[0] + GS[0] + GD[0];                                       \
            float h1 = P[1] + GS[1] + GD[1];                                       \
            float h2 = P[2] + GS[2] + GD[2];                                       \
            float h3 = P[3] + GS[3] + GD[3];                                       \
            h0 = h0 > 0.f ? h0 : __expf(h0) - 1.f;                                 \
            h1 = h1 > 0.f ? h1 : __expf(h1) - 1.f;                                 \
            h2 = h2 > 0.f ? h2 : __expf(h2) - 1.f;                                 \
            h3 = h3 > 0.f ? h3 : __expf(h3) - 1.f;                                 \
            u32x2 uu; uu[0] = pk2(h0, h1); uu[1] = pk2(h2, h3);                    \
            *(u32x2*)(&hw[e * 36 + 8 * M + 2 * g]) = uu;                           \
        }
        L1(0, gs0, gd0)
        L1(1, gs1, gd1)
        L1(2, gs2, gd2)
        L1(3, gs3, gd3)
#undef L1
        asm volatile("" ::: "memory");      // LDS writes before frag reads

        i32x4 hf0 = *(const i32x4*)(&hw[e * 36 + 4 * g]);        // ks=0: k=8g+i
        i32x4 hf1 = *(const i32x4*)(&hw[e * 36 + 16 + 4 * g]);   // ks=1: k=32+8g+i
        bf16x8 B0 = __builtin_bit_cast(bf16x8, hf0);
        bf16x8 B1 = __builtin_bit_cast(bf16x8, hf1);

#define L2(M2)                                                                     \
        {                                                                          \
            bf16x8 A0 = *(const bf16x8*)(sWoF + ((M2 * 2 + 0) * 64 + lane) * 8);   \
            bf16x8 A1 = *(const bf16x8*)(sWoF + ((M2 * 2 + 1) * 64 + lane) * 8);   \
            f32x4 o = __builtin_amdgcn_mfma_f32_16x16x32_bf16(A0, B0, boA[M2], 0, 0, 0); \
            o = __builtin_amdgcn_mfma_f32_16x16x32_bf16(A1, B1, o, 0, 0, 0);       \
            __builtin_nontemporal_store(o, (f32x4*)(out + (size_t)erow * 64 + 16 * M2 + 4 * g)); \
        }
        L2(0)
        L2(1)
        L2(2)
        L2(3)
#undef L2

        sv = svn; dv = dvn; ev0 = ev0n; ev1 = ev1n;
        asm volatile("" ::: "memory");      // frag reads done before next tile's writes
    }
}

extern "C" void kernel_launch(void* const* d_in, const int* in_sizes, int n_in,
                              void* d_out, int out_size, void* d_ws, size_t ws_size,
                              hipStream_t stream) {
    const float* h   = (const float*)d_in[0];
    const float* e   = (const float*)d_in[1];
    const float* eij = (const float*)d_in[2];
    const int*   src = (const int*)d_in[3];
    const int*   dst = (const int*)d_in[4];
    const float* W1  = (const float*)d_in[5];
    const float* b1  = (const float*)d_in[6];
    const float* W2  = (const float*)d_in[7];
    const float* b2  = (const float*)d_in[8];
    const float* W3  = (const float*)d_in[9];
    const float* b3  = (const float*)d_in[10];
    const float* Wh  = (const float*)d_in[11];
    const float* bh  = (const float*)d_in[12];
    const float* Wo  = (const float*)d_in[13];
    const float* bo  = (const float*)d_in[14];
    float* out = (float*)d_out;

    float* n2   = (float*)d_ws;                        // 80000*64 f32 = 20.48 MB
    short* W35F = (short*)(n2 + (size_t)NNODES * 64);  // 2048 bf16 (A-frag order)
    short* WoF  = W35F + 2048;                         // 4096 bf16 (A-frag order)
    float* c    = (float*)(WoF + 4096);                // 64 f32

    hipLaunchKernelGGL(k_pre, dim3(1), dim3(1024), 0, stream, W3, b3, Wh, bh, Wo, W35F, WoF, c);
    hipLaunchKernelGGL(k_node, dim3(1000), dim3(256), 0, stream,
                       h, e, W1, b1, W2, b2, Wh, c, n2);
    // 2500 blocks * 4 waves * 8 tiles * 16 edges = 1,280,000
    hipLaunchKernelGGL(k_edge, dim3(2500), dim3(256), 0, stream,
                       eij, src, dst, n2, W35F, WoF, bo, out);
}

// Round 6
// 247.574 us; speedup vs baseline: 1.0883x; 1.0150x over previous
//
#include <hip/hip_runtime.h>
#include <math.h>

constexpr int NNODES = 80000;
constexpr int NEDGES = 1280000;

typedef __attribute__((ext_vector_type(8))) short bf16x8;
typedef __attribute__((ext_vector_type(4))) float f32x4;
typedef __attribute__((ext_vector_type(4))) int i32x4;
typedef __attribute__((ext_vector_type(2))) unsigned u32x2;

__device__ __forceinline__ short f2b(float f) {
    unsigned u = __builtin_bit_cast(unsigned, f);
    u = u + 0x7FFFu + ((u >> 16) & 1u);          // RNE to bf16
    return (short)(u >> 16);
}
__device__ __forceinline__ unsigned pk2(float lo, float hi) {
    return ((unsigned)(unsigned short)f2b(hi) << 16) | (unsigned)(unsigned short)f2b(lo);
}

// K0: fold W3/b3 through Wh; emit per-lane A-fragments for 16x16x32 MFMA.
// A-frag at lane l: A[row = l&15][k = 8*(l>>4) + i], i=0..7.
// W35F[m*512 + l*8 + i] = W35[16m + (l&15)][8*(l>>4)+i]  (0 for k>=16)
// WoF [f*512 + l*8 + i] = Wo [16*(f>>1) + (l&15)][32*(f&1) + 8*(l>>4) + i]
// c[j] = bh[j] + sum_m Wh[j][m]*b3[m]
__global__ void k_pre(const float* __restrict__ W3, const float* __restrict__ b3,
                      const float* __restrict__ Wh, const float* __restrict__ bh,
                      const float* __restrict__ Wo,
                      short* __restrict__ W35F, short* __restrict__ WoF,
                      float* __restrict__ c) {
    int t = threadIdx.x;            // 1024 threads
#pragma unroll
    for (int r = 0; r < 2; ++r) {
        int idx = r * 1024 + t;
        int m = idx >> 9, l = (idx >> 3) & 63, i = idx & 7;
        int k = 8 * (l >> 4) + i;
        int ch = 16 * m + (l & 15);
        float s = 0.f;
        if (k < 16) {
#pragma unroll
            for (int mm = 0; mm < 64; ++mm) s += Wh[ch * 64 + mm] * W3[mm * 16 + k];
        }
        W35F[idx] = f2b(s);
    }
#pragma unroll
    for (int r = 0; r < 4; ++r) {
        int idx = r * 1024 + t;
        int f = idx >> 9, l = (idx >> 3) & 63, i = idx & 7;
        int ch = 16 * (f >> 1) + (l & 15);
        int k = 32 * (f & 1) + 8 * (l >> 4) + i;
        WoF[idx] = f2b(Wo[ch * 64 + k]);
    }
    if (t < 64) {
        float cc = bh[t];
#pragma unroll
        for (int m = 0; m < 64; ++m) cc += Wh[t * 64 + m] * b3[m];
        c[t] = cc;
    }
}

// K1: per-node  n2' = (h@W1^T + b1 + e@W2^T + b2) @ Wh^T + 0.5*c
__global__ __launch_bounds__(256) void k_node(
    const float* __restrict__ h, const float* __restrict__ e,
    const float* __restrict__ W1, const float* __restrict__ b1,
    const float* __restrict__ W2, const float* __restrict__ b2,
    const float* __restrict__ Wh, const float* __restrict__ c,
    float* __restrict__ n2) {
    __shared__ float sW1T[64 * 65];
    __shared__ float sW2T[32 * 65];
    __shared__ float sWhT[64 * 65];
    __shared__ float sStage[4][160];

    int tid = threadIdx.x;
    for (int idx = tid; idx < 64 * 64; idx += 256) {
        int j = idx >> 6, k = idx & 63;
        sW1T[k * 65 + j] = W1[idx];
        sWhT[k * 65 + j] = Wh[idx];
    }
    for (int idx = tid; idx < 64 * 32; idx += 256) {
        int j = idx >> 5, k = idx & 31;
        sW2T[k * 65 + j] = W2[idx];
    }
    __syncthreads();

    int w = tid >> 6, lane = tid & 63;
    float* hs = &sStage[w][0];
    float* es = &sStage[w][64];
    float* ns = &sStage[w][96];
    int waveId = blockIdx.x * 4 + w;
    float bb = b1[lane] + b2[lane];
    float chalf = 0.5f * c[lane];

    for (int i = 0; i < 20; ++i) {
        int n = waveId * 20 + i;
        hs[lane] = h[n * 64 + lane];
        if (lane < 32) es[lane] = e[n * 32 + lane];
        float a = bb;
#pragma unroll
        for (int k = 0; k < 64; ++k) a += hs[k] * sW1T[k * 65 + lane];
#pragma unroll
        for (int k = 0; k < 32; ++k) a += es[k] * sW2T[k * 65 + lane];
        ns[lane] = a;
        float o = chalf;
#pragma unroll
        for (int k = 0; k < 64; ++k) o += ns[k] * sWhT[k * 65 + lane];
        n2[n * 64 + lane] = o;
    }
}

// K2: 16-edge tiles, 16x16x32 MFMA, software-pipelined:
//   iter t:  issue idx[t+2]; issue n2-gathers[t+1] (idx resident);
//            issue eij[t+1]; compute tile t on gathers issued last iter.
__global__ __launch_bounds__(256, 3) void k_edge(
    const float* __restrict__ eij, const int* __restrict__ src, const int* __restrict__ dst,
    const float* __restrict__ n2, const short* __restrict__ W35F, const short* __restrict__ WoF,
    const float* __restrict__ bo, float* __restrict__ out) {
    __shared__ __align__(16) short sWoF[4096];       // 8 KB: [f][lane][i]
    __shared__ __align__(16) unsigned shm[4][576];   // per-wave hm redistribution

    int tid = threadIdx.x, w = tid >> 6, lane = tid & 63;
    int e = lane & 15, g = lane >> 4;

    for (int idx = tid; idx < 512; idx += 256)
        ((ulonglong2*)sWoF)[idx] = ((const ulonglong2*)WoF)[idx];
    __syncthreads();

    bf16x8 w35[4];
#pragma unroll
    for (int m = 0; m < 4; ++m)
        w35[m] = *(const bf16x8*)(W35F + (m * 64 + lane) * 8);
    f32x4 boA[4];
#pragma unroll
    for (int m2 = 0; m2 < 4; ++m2)
        boA[m2] = *(const f32x4*)(bo + 16 * m2 + 4 * g);

    unsigned* hw = shm[w];
    const int eoff = (g & 1) * 8;
    const bool glow = (g < 2);

    int gw = blockIdx.x * 4 + w;        // 0..9999
    int base = gw * 128;                // 8 tiles * 16 edges

    int sv[3], dv[3];
    f32x4 ev0[2], ev1[2];
    f32x4 gs[2][4], gd[2][4];

    // prologue: idx for tiles 0,1; eij tile 0; gathers tile 0
    sv[0] = src[base + e];      dv[0] = dst[base + e];
    sv[1] = src[base + 16 + e]; dv[1] = dst[base + 16 + e];
    ev0[0] = *(const f32x4*)(eij + (size_t)(base + e) * 16 + eoff);
    ev1[0] = *(const f32x4*)(eij + (size_t)(base + e) * 16 + eoff + 4);
    {
        const float* ps = n2 + (size_t)sv[0] * 64 + 4 * g;
        const float* pd = n2 + (size_t)dv[0] * 64 + 4 * g;
#pragma unroll
        for (int q = 0; q < 4; ++q) {
            gs[0][q] = *(const f32x4*)(ps + 16 * q);
            gd[0][q] = *(const f32x4*)(pd + 16 * q);
        }
    }

#pragma unroll
    for (int t = 0; t < 8; ++t) {
        const int cur = t & 1, nxt = cur ^ 1;

        // 1. idx prefetch for t+2
        if (t < 6) {
            int r = base + (t + 2) * 16 + e;
            sv[(t + 2) % 3] = src[r];
            dv[(t + 2) % 3] = dst[r];
        }
        // 2. n2 gathers for t+1 (idx arrived last iter); 3. eij for t+1
        if (t < 7) {
            const float* ps = n2 + (size_t)sv[(t + 1) % 3] * 64 + 4 * g;
            const float* pd = n2 + (size_t)dv[(t + 1) % 3] * 64 + 4 * g;
#pragma unroll
            for (int q = 0; q < 4; ++q) {
                gs[nxt][q] = *(const f32x4*)(ps + 16 * q);
                gd[nxt][q] = *(const f32x4*)(pd + 16 * q);
            }
            int r = base + (t + 1) * 16 + e;
            ev0[nxt] = *(const f32x4*)(eij + (size_t)r * 16 + eoff);
            ev1[nxt] = *(const f32x4*)(eij + (size_t)r * 16 + eoff + 4);
        }

        // 4. compute tile t
        int erow = base + t * 16 + e;
        i32x4 ebi;
        ebi[0] = glow ? (int)pk2(ev0[cur][0], ev0[cur][1]) : 0;
        ebi[1] = glow ? (int)pk2(ev0[cur][2], ev0[cur][3]) : 0;
        ebi[2] = glow ? (int)pk2(ev1[cur][0], ev1[cur][1]) : 0;
        ebi[3] = glow ? (int)pk2(ev1[cur][2], ev1[cur][3]) : 0;
        bf16x8 eb = __builtin_bit_cast(bf16x8, ebi);

        const f32x4 z4 = {0.f, 0.f, 0.f, 0.f};
#define L1(M)                                                                      \
        {                                                                          \
            f32x4 P = __builtin_amdgcn_mfma_f32_16x16x32_bf16(w35[M], eb, z4, 0, 0, 0); \
            float h0 = P[0] + gs[cur][M][0] + gd[cur][M][0];                       \
            float h1 = P[1] + gs[cur][M][1] + gd[cur][M][1];                       \
            float h2 = P[2] + gs[cur][M][2] + gd[cur][M][2];                       \
            float h3 = P[3] + gs[cur][M][3] + gd[cur][M][3];                       \
            h0 = h0 > 0.f ? h0 : __expf(h0) - 1.f;                                 \
            h1 = h1 > 0.f ? h1 : __expf(h1) - 1.f;                                 \
            h2 = h2 > 0.f ? h2 : __expf(h2) - 1.f;                                 \
            h3 = h3 > 0.f ? h3 : __expf(h3) - 1.f;                                 \
            u32x2 uu; uu[0] = pk2(h0, h1); uu[1] = pk2(h2, h3);                    \
            *(u32x2*)(&hw[e * 36 + 8 * M + 2 * g]) = uu;                           \
        }
        L1(0)
        L1(1)
        L1(2)
        L1(3)
#undef L1
        asm volatile("" ::: "memory");      // LDS writes before frag reads

        i32x4 hf0 = *(const i32x4*)(&hw[e * 36 + 4 * g]);        // ks=0: k=8g+i
        i32x4 hf1 = *(const i32x4*)(&hw[e * 36 + 16 + 4 * g]);   // ks=1: k=32+8g+i
        bf16x8 B0 = __builtin_bit_cast(bf16x8, hf0);
        bf16x8 B1 = __builtin_bit_cast(bf16x8, hf1);

#define L2(M2)                                                                     \
        {                                                                          \
            bf16x8 A0 = *(const bf16x8*)(sWoF + ((M2 * 2 + 0) * 64 + lane) * 8);   \
            bf16x8 A1 = *(const bf16x8*)(sWoF + ((M2 * 2 + 1) * 64 + lane) * 8);   \
            f32x4 o = __builtin_amdgcn_mfma_f32_16x16x32_bf16(A0, B0, boA[M2], 0, 0, 0); \
            o = __builtin_amdgcn_mfma_f32_16x16x32_bf16(A1, B1, o, 0, 0, 0);       \
            __builtin_nontemporal_store(o, (f32x4*)(out + (size_t)erow * 64 + 16 * M2 + 4 * g)); \
        }
        L2(0)
        L2(1)
        L2(2)
        L2(3)
#undef L2
        asm volatile("" ::: "memory");      // frag reads done before next tile's writes
    }
}

extern "C" void kernel_launch(void* const* d_in, const int* in_sizes, int n_in,
                              void* d_out, int out_size, void* d_ws, size_t ws_size,
                              hipStream_t stream) {
    const float* h   = (const float*)d_in[0];
    const float* e   = (const float*)d_in[1];
    const float* eij = (const float*)d_in[2];
    const int*   src = (const int*)d_in[3];
    const int*   dst = (const int*)d_in[4];
    const float* W1  = (const float*)d_in[5];
    const float* b1  = (const float*)d_in[6];
    const float* W2  = (const float*)d_in[7];
    const float* b2  = (const float*)d_in[8];
    const float* W3  = (const float*)d_in[9];
    const float* b3  = (const float*)d_in[10];
    const float* Wh  = (const float*)d_in[11];
    const float* bh  = (const float*)d_in[12];
    const float* Wo  = (const float*)d_in[13];
    const float* bo  = (const float*)d_in[14];
    float* out = (float*)d_out;

    float* n2   = (float*)d_ws;                        // 80000*64 f32 = 20.48 MB
    short* W35F = (short*)(n2 + (size_t)NNODES * 64);  // 2048 bf16 (A-frag order)
    short* WoF  = W35F + 2048;                         // 4096 bf16 (A-frag order)
    float* c    = (float*)(WoF + 4096);                // 64 f32

    hipLaunchKernelGGL(k_pre, dim3(1), dim3(1024), 0, stream, W3, b3, Wh, bh, Wo, W35F, WoF, c);
    hipLaunchKernelGGL(k_node, dim3(1000), dim3(256), 0, stream,
                       h, e, W1, b1, W2, b2, Wh, c, n2);
    // 2500 blocks * 4 waves * 8 tiles * 16 edges = 1,280,000
    hipLaunchKernelGGL(k_edge, dim3(2500), dim3(256), 0, stream,
                       eij, src, dst, n2, W35F, WoF, bo, out);
}